// Round 4
// baseline (498.604 us; speedup 1.0000x reference)
//
#include <hip/hip_runtime.h>
#include <hip/hip_bf16.h>
#include <stdint.h>

#define NBATCH 512
#define FDIM   512   // graph_feat_size
#define NATOM  128   // N
#define KDIM   256   // attention K
#define NT     16    // f-tiles of 32

#define VS_STRIDE 40    // VsT row stride (ushorts): 80B rows, b128-aligned, ~2-way reads

// padded cgate index: bank-conflict-free gather for k-chunked reads
#define CGI(k) ((k) + ((k) >> 5))

typedef __attribute__((ext_vector_type(8))) __bf16         bf16x8;
typedef __attribute__((ext_vector_type(8))) unsigned short ushort8;
typedef __attribute__((ext_vector_type(4))) unsigned short ushort4v;
typedef __attribute__((ext_vector_type(4))) float          f32x4;

__device__ __forceinline__ float fast_tanh(float x) {
    float e = __expf(2.0f * x);
    return 1.0f - 2.0f / (e + 1.0f);
}
__device__ __forceinline__ unsigned short bf16_rne(float f) {
    unsigned int u = __float_as_uint(f);
    u += 0x7FFFu + ((u >> 16) & 1u);   // round-to-nearest-even
    return (unsigned short)(u >> 16);
}
__device__ __forceinline__ float bf16_to_f(unsigned short h) {
    return __uint_as_float(((unsigned int)h) << 16);
}
__device__ __forceinline__ bf16x8 ldfrag(const unsigned short* p) {
    return __builtin_bit_cast(bf16x8, *(const ushort8*)p);
}
__device__ __forceinline__ void glds16(const unsigned short* g, unsigned short* l) {
    __builtin_amdgcn_global_load_lds(
        (const __attribute__((address_space(1))) unsigned int*)g,
        (__attribute__((address_space(3))) unsigned int*)l, 16, 0, 0);
}
__device__ __forceinline__ float dot4(float4 a, float4 b) {
    return a.x * b.x + a.y * b.y + a.z * b.z + a.w * b.w;
}

// ---- pre-kernel: W_v, W_q f32 [256x512] -> per-tile-contiguous bf16 image ----
// layout (ushort): [side][s][k][fo]  flat = ((side*16+s)*256 + k)*32 + fo
__global__ __launch_bounds__(256)
void wconv_kernel(const float* __restrict__ Wv, const float* __restrict__ Wq,
                  unsigned short* __restrict__ out) {
    int i = blockIdx.x * 256 + threadIdx.x;   // 32768 threads: side|s|k|c
    int c = i & 3, k = (i >> 2) & 255, s = (i >> 10) & 15, side = i >> 14;
    const float* W = side ? Wq : Wv;
    const float4* p = (const float4*)(W + (size_t)k * FDIM + s * 32 + c * 8);
    float4 a = p[0], b2 = p[1];
    ushort8 o;
    o[0] = bf16_rne(a.x);  o[1] = bf16_rne(a.y);
    o[2] = bf16_rne(a.z);  o[3] = bf16_rne(a.w);
    o[4] = bf16_rne(b2.x); o[5] = bf16_rne(b2.y);
    o[6] = bf16_rne(b2.z); o[7] = bf16_rne(b2.w);
    *(ushort8*)(out + (size_t)i * 8) = o;
}

__global__ __launch_bounds__(1024, 8)
void coattn_kernel(const float* __restrict__ V_n, const float* __restrict__ Q_n,
                   const float* __restrict__ W_m, const float* __restrict__ W_h,
                   const unsigned short* __restrict__ Wt,
                   unsigned short* __restrict__ Gv_ws,
                   float* __restrict__ out)
{
    __shared__ unsigned short Ws[2][KDIM * 32];          // 32768 B (glds dest, linear)
    __shared__ unsigned short VsT[2][NATOM * VS_STRIDE]; // 20480 B
    __shared__ float rsV[FDIM], rsQ[FDIM], m0s[FDIM];    //  6144 B
    __shared__ float cgateP[KDIM + KDIM / 32];           //  1056 B
    __shared__ float sV[NATOM], sQ[NATOM], alV[NATOM], alQ[NATOM]; // 2048 B

    const int b    = blockIdx.x;
    const int t    = threadIdx.x;
    const int lane = t & 63;
    const int wid  = t >> 6;      // 0..15
    const int wr   = wid >> 1;    // 0..7 : k-block of 32
    const int wc   = wid & 1;     // 0..1 : n-block of 64
    const int l15  = lane & 15;
    const int lg   = lane >> 4;   // 0..3
    const int fr   = t >> 5;      // 0..31 : f-row in staging
    const int m    = t & 31;      // n-coarse in staging

    const float* Vb = V_n + (size_t)b * FDIM * NATOM;
    const float* Qb = Q_n + (size_t)b * FDIM * NATOM;
    unsigned short* Gvb = Gv_ws + (size_t)b * (KDIM * NATOM);   // [n][k] bf16

    f32x4 acc[2][4];

    const int aoff = (wr * 32 + l15) * 32 + lg * 8;
    const int boff = (wc * 64 + l15) * VS_STRIDE + lg * 8;

    auto stream_gemm = [&](const float* src, const unsigned short* Wside,
                           float* rowsum) {
        {
            f32x4 z = {0.f, 0.f, 0.f, 0.f};
            #pragma unroll
            for (int i = 0; i < 2; ++i)
                #pragma unroll
                for (int j = 0; j < 4; ++j) acc[i][j] = z;
        }
        float vv[2][4];
        auto vload = [&](int s, int buf) {
            const float* p = src + (size_t)(s * 32 + fr) * NATOM + m;
            #pragma unroll
            for (int i = 0; i < 4; ++i) vv[buf][i] = p[32 * i];
        };
        auto vstore = [&](int s, int buf) {
            float rs = vv[buf][0] + vv[buf][1] + vv[buf][2] + vv[buf][3];
            rs += __shfl_xor(rs, 1);
            rs += __shfl_xor(rs, 2);
            rs += __shfl_xor(rs, 4);
            rs += __shfl_xor(rs, 8);
            rs += __shfl_xor(rs, 16);
            if (m == 0) rowsum[s * 32 + fr] = rs;
            #pragma unroll
            for (int i = 0; i < 4; ++i)
                VsT[buf][(m + 32 * i) * VS_STRIDE + fr] = bf16_rne(vv[buf][i]);
        };
        auto wstage = [&](int s, int buf) {
            glds16(Wside + (size_t)s * 8192 + wid * 512 + lane * 8,
                   &Ws[buf][wid * 512]);
        };

        vload(0, 0);
        vstore(0, 0);
        wstage(0, 0);
        vload(1, 1);
        __syncthreads();

        #pragma unroll
        for (int s = 0; s < NT; ++s) {
            const int cur = s & 1;
            // issue-early: fill the *other* buffer and launch next-next loads
            // BEFORE the fragment-read + MFMA phase, so the end-of-iter
            // vmcnt(0) drain waits on loads that are already ~1 iter old.
            if (s + 1 < NT) { vstore(s + 1, cur ^ 1); wstage(s + 1, cur ^ 1); }
            if (s + 2 < NT) vload(s + 2, cur);

            bf16x8 af[2], bfr[4];
            #pragma unroll
            for (int mi = 0; mi < 2; ++mi)
                af[mi] = ldfrag(&Ws[cur][aoff + mi * 512]);
            #pragma unroll
            for (int ni = 0; ni < 4; ++ni)
                bfr[ni] = ldfrag(&VsT[cur][boff + ni * 16 * VS_STRIDE]);

            #pragma unroll
            for (int mi = 0; mi < 2; ++mi)
                #pragma unroll
                for (int ni = 0; ni < 4; ++ni)
                    acc[mi][ni] = __builtin_amdgcn_mfma_f32_16x16x32_bf16(
                        af[mi], bfr[ni], acc[mi][ni], 0, 0, 0);
            __syncthreads();
        }
    };

    // ---- V pass; spill tanh(Gv) to global scratch (L2-hot); reuse acc ----
    stream_gemm(Vb, Wt, rsV);

    #pragma unroll
    for (int mi = 0; mi < 2; ++mi)
        #pragma unroll
        for (int ni = 0; ni < 4; ++ni) {
            ushort4v p;
            #pragma unroll
            for (int j = 0; j < 4; ++j)
                p[j] = bf16_rne(fast_tanh(acc[mi][ni][j]));
            const int k0 = wr * 32 + mi * 16 + lg * 4;
            const int n  = wc * 64 + ni * 16 + l15;
            *(ushort4v*)(Gvb + (size_t)n * KDIM + k0) = p;
        }

    stream_gemm(Qb, Wt + 16 * 8192, rsQ);

    __syncthreads();
    if (t < FDIM)
        m0s[t] = fast_tanh(rsV[t] * 0.015625f) * fast_tanh(rsQ[t] * 0.015625f);
    if (t < NATOM) sQ[t] = 0.f;
    __syncthreads();

    // ---- gate GEMV: cgate[k] = tanh(W_m[k,:] . M0) * W_h[k] ----
    {
        const float4* m04 = (const float4*)m0s;
        float4 mb0 = m04[2 * lane], mb1 = m04[2 * lane + 1];
        #pragma unroll
        for (int kk = wid; kk < KDIM; kk += 16) {
            const float4* wm4 = (const float4*)(W_m + (size_t)kk * FDIM);
            float4 a0 = wm4[2 * lane], a1 = wm4[2 * lane + 1];
            float sum = dot4(a0, mb0) + dot4(a1, mb1);
            #pragma unroll
            for (int o = 1; o < 64; o <<= 1) sum += __shfl_xor(sum, o);
            if (lane == 0) cgateP[CGI(kk)] = fast_tanh(sum) * W_h[kk];
        }
    }
    __syncthreads();

    // ---- sV (from Gv scratch, no atomics) + sQ (from live acc) ----
    {
        // issue Gv loads first so HBM/L2 latency hides under sQ compute
        const unsigned short* gvp = Gvb + (size_t)(t >> 3) * KDIM + (t & 7) * 32;
        ushort8 g0 = ((const ushort8*)gvp)[0];
        ushort8 g1 = ((const ushort8*)gvp)[1];
        ushort8 g2 = ((const ushort8*)gvp)[2];
        ushort8 g3 = ((const ushort8*)gvp)[3];

        // sQ: each thread folds its acc fragment
        float sp[4] = {0.f, 0.f, 0.f, 0.f};
        #pragma unroll
        for (int mi = 0; mi < 2; ++mi)
            #pragma unroll
            for (int j = 0; j < 4; ++j) {
                const float c = cgateP[CGI(wr * 32 + mi * 16 + lg * 4 + j)];
                #pragma unroll
                for (int ni = 0; ni < 4; ++ni)
                    sp[ni] += c * fast_tanh(acc[mi][ni][j]);
            }
        #pragma unroll
        for (int ni = 0; ni < 4; ++ni) {
            sp[ni] += __shfl_xor(sp[ni], 16);
            sp[ni] += __shfl_xor(sp[ni], 32);
        }
        if (lg == 0) {
            #pragma unroll
            for (int ni = 0; ni < 4; ++ni)
                atomicAdd(&sQ[wc * 64 + ni * 16 + l15], sp[ni]);
        }

        // sV: 8 lanes per n, 32 k each -> full dot, no atomics
        const int kb = (t & 7) * 32;
        float pv = 0.f;
        #pragma unroll
        for (int i = 0; i < 8; ++i) {
            pv += cgateP[CGI(kb + i)]      * bf16_to_f((unsigned short)g0[i]);
            pv += cgateP[CGI(kb + 8 + i)]  * bf16_to_f((unsigned short)g1[i]);
            pv += cgateP[CGI(kb + 16 + i)] * bf16_to_f((unsigned short)g2[i]);
            pv += cgateP[CGI(kb + 24 + i)] * bf16_to_f((unsigned short)g3[i]);
        }
        pv += __shfl_xor(pv, 1);
        pv += __shfl_xor(pv, 2);
        pv += __shfl_xor(pv, 4);
        if ((t & 7) == 0) sV[t >> 3] = pv;
    }
    __syncthreads();

    // ---- softmax: wave0 -> V, wave1 -> Q ----
    if (wid < 2) {
        float* sarr = wid ? sQ : sV;
        float* aarr = wid ? alQ : alV;
        float* oal  = out + 2 * (size_t)NBATCH * FDIM
                    + (size_t)wid * NBATCH * NATOM + (size_t)b * NATOM;
        float a  = sarr[lane];
        float c2 = sarr[64 + lane];
        float mx = fmaxf(a, c2);
        #pragma unroll
        for (int o = 1; o < 64; o <<= 1) mx = fmaxf(mx, __shfl_xor(mx, o));
        float ea = __expf(a - mx), eb = __expf(c2 - mx);
        float ssum = ea + eb;
        #pragma unroll
        for (int o = 1; o < 64; o <<= 1) ssum += __shfl_xor(ssum, o);
        float inv = 1.0f / ssum;
        ea *= inv; eb *= inv;
        aarr[lane] = ea; aarr[64 + lane] = eb;
        oal[lane]  = ea; oal[64 + lane]  = eb;
    }
    __syncthreads();

    // ---- weighted sums: 8-lane-group dots, float4 loads, 3-shuffle reduce ----
    {
        const int fo = t >> 3;          // 0..127
        const int n4 = (t & 7) * 4;     // float4 index into alpha
        const float4* alv4 = (const float4*)alV;
        float4 av0 = alv4[n4], av1 = alv4[n4 + 1], av2 = alv4[n4 + 2], av3 = alv4[n4 + 3];
        float* ovV = out + (size_t)b * FDIM;
        #pragma unroll
        for (int pass = 0; pass < 4; ++pass) {
            const int f = pass * 128 + fo;
            const float4* vp = (const float4*)(Vb + (size_t)f * NATOM + n4 * 4);
            float s = dot4(vp[0], av0) + dot4(vp[1], av1)
                    + dot4(vp[2], av2) + dot4(vp[3], av3);
            s += __shfl_xor(s, 1);
            s += __shfl_xor(s, 2);
            s += __shfl_xor(s, 4);
            if ((t & 7) == 0) ovV[f] = s;
        }
        const float4* alq4 = (const float4*)alQ;
        float4 aq0 = alq4[n4], aq1 = alq4[n4 + 1], aq2 = alq4[n4 + 2], aq3 = alq4[n4 + 3];
        float* ovQ = out + (size_t)NBATCH * FDIM + (size_t)b * FDIM;
        #pragma unroll
        for (int pass = 0; pass < 4; ++pass) {
            const int f = pass * 128 + fo;
            const float4* qp = (const float4*)(Qb + (size_t)f * NATOM + n4 * 4);
            float s = dot4(qp[0], aq0) + dot4(qp[1], aq1)
                    + dot4(qp[2], aq2) + dot4(qp[3], aq3);
            s += __shfl_xor(s, 1);
            s += __shfl_xor(s, 2);
            s += __shfl_xor(s, 4);
            if ((t & 7) == 0) ovQ[f] = s;
        }
    }
}

extern "C" void kernel_launch(void* const* d_in, const int* in_sizes, int n_in,
                              void* d_out, int out_size, void* d_ws, size_t ws_size,
                              hipStream_t stream) {
    (void)in_sizes; (void)n_in; (void)out_size; (void)ws_size;
    const float* V_n = (const float*)d_in[0];
    const float* Q_n = (const float*)d_in[1];
    const float* W_m = (const float*)d_in[2];
    const float* W_v = (const float*)d_in[3];
    const float* W_q = (const float*)d_in[4];
    const float* W_h = (const float*)d_in[5];
    float* out = (float*)d_out;

    unsigned short* Wt    = (unsigned short*)d_ws;          // 512 KB tiled bf16 W image
    unsigned short* Gv_ws = Wt + 2 * 16 * 8192;             // 32 MB: [b][n][k] bf16

    hipLaunchKernelGGL(wconv_kernel, dim3(128), dim3(256), 0, stream,
                       W_v, W_q, Wt);
    hipLaunchKernelGGL(coattn_kernel, dim3(NBATCH), dim3(1024), 0, stream,
                       V_n, Q_n, W_m, W_h, Wt, Gv_ws, out);
}